// Round 1
// baseline (330.539 us; speedup 1.0000x reference)
//
#include <hip/hip_runtime.h>
#include <math.h>

// NoisyTopKGating: N=16384 rows, D=2048, E=64 experts, top-2.
// out layout (f32, concatenated): weights [N,2] @0, indices-as-float [N,2] @32768,
// clean_logits [N,64] @65536.

constexpr int NROWS = 16384;
constexpr int DDIM  = 2048;
constexpr int EDIM  = 64;
constexpr int BM    = 64;   // rows per block
constexpr int BK    = 32;   // K chunk
constexpr int KST   = BK + 4;   // padded LDS stride (floats); 4-float pad keeps 16B align,
                                // reduces row-group aliasing to 2-way (free, m136)
constexpr int IDX_OFF   = NROWS * 2;       // 32768
constexpr int CLEAN_OFF = NROWS * 4;       // 65536

__device__ __forceinline__ float softplus_f(float z) {
    // jax.nn.softplus = max(z,0) + log1p(exp(-|z|))  (stable form)
    return fmaxf(z, 0.0f) + log1pf(expf(-fabsf(z)));
}

__global__ __launch_bounds__(256) void gating_kernel(
    const float* __restrict__ x,
    const float* __restrict__ Wg,
    const float* __restrict__ Wn,
    const float* __restrict__ noise,
    float* __restrict__ out)
{
    __shared__ float smem[3 * BM * KST];       // 6912 floats = 27.6 KB
    float* xs  = smem;
    float* wgs = smem + BM * KST;
    float* wns = smem + 2 * BM * KST;

    const int tid = threadIdx.x;
    const int row_base = blockIdx.x * BM;
    const int et = tid & 15;        // expert group (4 experts)
    const int rt = tid >> 4;        // row group (4 rows)
    const int e0 = et * 4;
    const int r0 = rt * 4;

    float accg[4][4];
    float accn[4][4];
    #pragma unroll
    for (int i = 0; i < 4; ++i)
        #pragma unroll
        for (int j = 0; j < 4; ++j) { accg[i][j] = 0.0f; accn[i][j] = 0.0f; }

    for (int k0 = 0; k0 < DDIM; k0 += BK) {
        // ---- stage x tile [64][32] and W tiles [64][32] (2 matrices) ----
        #pragma unroll
        for (int p = 0; p < 2; ++p) {
            const int f  = tid + p * 256;      // float4 id 0..511
            const int r  = f >> 3;             // row / expert
            const int kq = (f & 7) << 2;       // float offset within chunk
            const size_t goff = (size_t)r * DDIM + k0 + kq;
            float4 xv = *reinterpret_cast<const float4*>(&x[(size_t)(row_base + r) * DDIM + k0 + kq]);
            *reinterpret_cast<float4*>(&xs[r * KST + kq]) = xv;
            float4 gv = *reinterpret_cast<const float4*>(&Wg[goff]);
            *reinterpret_cast<float4*>(&wgs[r * KST + kq]) = gv;
            float4 nv = *reinterpret_cast<const float4*>(&Wn[goff]);
            *reinterpret_cast<float4*>(&wns[r * KST + kq]) = nv;
        }
        __syncthreads();

        // ---- compute: 4 rows x 4 experts x 2 matrices ----
        #pragma unroll
        for (int kk = 0; kk < BK; kk += 4) {
            float4 xv[4];
            #pragma unroll
            for (int i = 0; i < 4; ++i)
                xv[i] = *reinterpret_cast<const float4*>(&xs[(r0 + i) * KST + kk]);
            #pragma unroll
            for (int j = 0; j < 4; ++j) {
                const float4 gv = *reinterpret_cast<const float4*>(&wgs[(e0 + j) * KST + kk]);
                const float4 nv = *reinterpret_cast<const float4*>(&wns[(e0 + j) * KST + kk]);
                #pragma unroll
                for (int i = 0; i < 4; ++i) {
                    float ag = accg[i][j];
                    ag = fmaf(xv[i].x, gv.x, ag);
                    ag = fmaf(xv[i].y, gv.y, ag);
                    ag = fmaf(xv[i].z, gv.z, ag);
                    ag = fmaf(xv[i].w, gv.w, ag);
                    accg[i][j] = ag;
                    float an = accn[i][j];
                    an = fmaf(xv[i].x, nv.x, an);
                    an = fmaf(xv[i].y, nv.y, an);
                    an = fmaf(xv[i].z, nv.z, an);
                    an = fmaf(xv[i].w, nv.w, an);
                    accn[i][j] = an;
                }
            }
        }
        __syncthreads();
    }

    // ---- epilogue: clean logits out, noisy logits into LDS ----
    float* noisy = smem;                        // [BM][68] = 4352 floats, reuses smem
    constexpr int NST = EDIM + 4;
    #pragma unroll
    for (int i = 0; i < 4; ++i) {
        const int row = row_base + r0 + i;
        float4 cg;
        cg.x = accg[i][0]; cg.y = accg[i][1]; cg.z = accg[i][2]; cg.w = accg[i][3];
        *reinterpret_cast<float4*>(&out[CLEAN_OFF + (size_t)row * EDIM + e0]) = cg;

        const float4 nz = *reinterpret_cast<const float4*>(&noise[(size_t)row * EDIM + e0]);
        float4 nv;
        nv.x = fmaf(softplus_f(accn[i][0]), nz.x, accg[i][0]);
        nv.y = fmaf(softplus_f(accn[i][1]), nz.y, accg[i][1]);
        nv.z = fmaf(softplus_f(accn[i][2]), nz.z, accg[i][2]);
        nv.w = fmaf(softplus_f(accn[i][3]), nz.w, accg[i][3]);
        *reinterpret_cast<float4*>(&noisy[(r0 + i) * NST + e0]) = nv;
    }
    __syncthreads();

    // ---- top-2 + softmax: one thread per row ----
    if (tid < BM) {
        const float* nr = &noisy[tid * NST];
        float v0 = -INFINITY, v1 = -INFINITY;
        int i0 = 0, i1 = 0;
        for (int e = 0; e < EDIM; ++e) {
            const float v = nr[e];
            if (v > v0) { v1 = v0; i1 = i0; v0 = v; i0 = e; }
            else if (v > v1) { v1 = v; i1 = e; }
        }
        const float ex = expf(v1 - v0);         // <= 1
        const float w0 = 1.0f / (1.0f + ex);
        const float w1 = ex * w0;
        const int row = row_base + tid;
        out[(size_t)row * 2 + 0] = w0;
        out[(size_t)row * 2 + 1] = w1;
        out[IDX_OFF + (size_t)row * 2 + 0] = (float)i0;
        out[IDX_OFF + (size_t)row * 2 + 1] = (float)i1;
    }
}

extern "C" void kernel_launch(void* const* d_in, const int* in_sizes, int n_in,
                              void* d_out, int out_size, void* d_ws, size_t ws_size,
                              hipStream_t stream) {
    const float* x     = (const float*)d_in[0];
    const float* Wg    = (const float*)d_in[1];
    const float* Wn    = (const float*)d_in[2];
    const float* noise = (const float*)d_in[3];
    float* out = (float*)d_out;

    dim3 grid(NROWS / BM);      // 256 blocks
    dim3 block(256);
    gating_kernel<<<grid, block, 0, stream>>>(x, Wg, Wn, noise, out);
}

// Round 2
// 80.615 us; speedup vs baseline: 4.1002x; 4.1002x over previous
//
#include <hip/hip_runtime.h>
#include <math.h>

// NoisyTopKGating via fp16x2-split MFMA.
// out layout (f32 flat): weights [N,2] @0, indices-as-float [N,2] @32768, clean [N,64] @65536.
// d_ws: wh [128][2048] f16 (512KB) @0, wl' (=(w-wh)*2048 as f16) @524288.

constexpr int NROWS = 16384;
constexpr int DDIM  = 2048;
constexpr int EDIM  = 64;
constexpr int ECOL  = 128;            // gate cols 0..63, noise cols 64..127
constexpr int BM    = 32;             // rows per block
constexpr int IDX_OFF   = NROWS * 2;
constexpr int CLEAN_OFF = NROWS * 4;

typedef _Float16 f16x8 __attribute__((ext_vector_type(8)));
typedef float    f32x4 __attribute__((ext_vector_type(4)));

__device__ __forceinline__ float softplus_f(float z) {
    return fmaxf(z, 0.0f) + log1pf(expf(-fabsf(z)));
}

// ---------- pre-kernel: split combined weights into f16 hi + scaled-lo ----------
__global__ __launch_bounds__(256) void split_w_kernel(
    const float* __restrict__ Wg, const float* __restrict__ Wn,
    _Float16* __restrict__ wh, _Float16* __restrict__ wl)
{
    const int t  = blockIdx.x * 256 + threadIdx.x;   // 0..65535
    const int E4 = t * 4;                            // element index (of 262144)
    const int row = E4 >> 11;                        // 0..127
    const int k   = E4 & 2047;
    const float* src = (row < 64) ? &Wg[(size_t)row * DDIM + k]
                                  : &Wn[(size_t)(row - 64) * DDIM + k];
    const float4 v = *reinterpret_cast<const float4*>(src);
    union { _Float16 h[4]; uint2 u; } hh, ll;
    hh.h[0] = (_Float16)v.x; ll.h[0] = (_Float16)((v.x - (float)hh.h[0]) * 2048.0f);
    hh.h[1] = (_Float16)v.y; ll.h[1] = (_Float16)((v.y - (float)hh.h[1]) * 2048.0f);
    hh.h[2] = (_Float16)v.z; ll.h[2] = (_Float16)((v.z - (float)hh.h[2]) * 2048.0f);
    hh.h[3] = (_Float16)v.w; ll.h[3] = (_Float16)((v.w - (float)hh.h[3]) * 2048.0f);
    *reinterpret_cast<uint2*>(&wh[E4]) = hh.u;
    *reinterpret_cast<uint2*>(&wl[E4]) = ll.u;
}

// ---------- main fused kernel ----------
__global__ __launch_bounds__(256) void gating_mfma_kernel(
    const float* __restrict__ x,
    const float* __restrict__ noise,
    const _Float16* __restrict__ whp,
    const _Float16* __restrict__ wlp,
    float* __restrict__ out)
{
    // LDS: x tiles, chunk-major [4 kchunks][32 rows][16B], xh then xl', double buffered:
    //   buf b at b*4096: xh @ +0 (2KB), xl @ +2048 (2KB).  Epilogue reuses as [32][128] f32.
    __shared__ __align__(16) unsigned char smem[16384];

    const int tid = threadIdx.x;
    const int row_base = blockIdx.x * BM;
    const int lane = tid & 63;
    const int wid  = tid >> 6;           // 0..3
    const int g    = lane >> 4;          // k-group 0..3
    const int idx  = lane & 15;          // row (A) / col (B) within frag
    const int colbase = wid * 32;

    // staging mapping: thread -> (chunk c, row r2, half hf)
    const int c  = tid >> 6;
    const int r2 = (tid >> 1) & 31;
    const int hf = tid & 1;
    const float* xg = x + (size_t)(row_base + r2) * DDIM + c * 8 + hf * 4;
    const int wr_off = c * 512 + r2 * 16 + hf * 8;   // byte offset in x tile

    // B pointers (per colfrag): col = colbase + cf*16 + idx
    const int colA = colbase + idx;
    const int colB = colbase + 16 + idx;
    const _Float16* bhA = whp + (size_t)colA * DDIM + g * 8;
    const _Float16* bhB = whp + (size_t)colB * DDIM + g * 8;
    const _Float16* blA = wlp + (size_t)colA * DDIM + g * 8;
    const _Float16* blB = wlp + (size_t)colB * DDIM + g * 8;

    f32x4 accm[2][2], accc[2][2];
    #pragma unroll
    for (int rf = 0; rf < 2; ++rf)
        #pragma unroll
        for (int cf = 0; cf < 2; ++cf) { accm[rf][cf] = (f32x4)0.0f; accc[rf][cf] = (f32x4)0.0f; }

    // ---- prologue: stage chunk 0, load B chunk 0 ----
    {
        const float4 xv = *reinterpret_cast<const float4*>(xg);
        union { _Float16 h[4]; uint2 u; } ph, pl;
        ph.h[0] = (_Float16)xv.x; pl.h[0] = (_Float16)((xv.x - (float)ph.h[0]) * 2048.0f);
        ph.h[1] = (_Float16)xv.y; pl.h[1] = (_Float16)((xv.y - (float)ph.h[1]) * 2048.0f);
        ph.h[2] = (_Float16)xv.z; pl.h[2] = (_Float16)((xv.z - (float)ph.h[2]) * 2048.0f);
        ph.h[3] = (_Float16)xv.w; pl.h[3] = (_Float16)((xv.w - (float)ph.h[3]) * 2048.0f);
        *reinterpret_cast<uint2*>(&smem[wr_off])        = ph.u;
        *reinterpret_cast<uint2*>(&smem[2048 + wr_off]) = pl.u;
    }
    f16x8 BhC[2], BlC[2];
    BhC[0] = *reinterpret_cast<const f16x8*>(bhA);
    BhC[1] = *reinterpret_cast<const f16x8*>(bhB);
    BlC[0] = *reinterpret_cast<const f16x8*>(blA);
    BlC[1] = *reinterpret_cast<const f16x8*>(blB);
    __syncthreads();

    // ---- K loop: 64 iterations of K=32 ----
    for (int t = 0; t < 64; ++t) {
        const bool last = (t == 63);
        float4 xn;
        f16x8 BhN[2], BlN[2];
        if (!last) {
            const int kn = (t + 1) * 32;
            xn = *reinterpret_cast<const float4*>(xg + kn);
            BhN[0] = *reinterpret_cast<const f16x8*>(bhA + kn);
            BhN[1] = *reinterpret_cast<const f16x8*>(bhB + kn);
            BlN[0] = *reinterpret_cast<const f16x8*>(blA + kn);
            BlN[1] = *reinterpret_cast<const f16x8*>(blB + kn);
        }

        const int base = (t & 1) * 4096;
        f16x8 Ah[2], Al[2];
        #pragma unroll
        for (int rf = 0; rf < 2; ++rf) {
            const int off = base + g * 512 + (rf * 16 + idx) * 16;
            Ah[rf] = *reinterpret_cast<const f16x8*>(&smem[off]);
            Al[rf] = *reinterpret_cast<const f16x8*>(&smem[off + 2048]);
        }
        #pragma unroll
        for (int rf = 0; rf < 2; ++rf)
            #pragma unroll
            for (int cf = 0; cf < 2; ++cf) {
                accm[rf][cf] = __builtin_amdgcn_mfma_f32_16x16x32_f16(Ah[rf], BhC[cf], accm[rf][cf], 0, 0, 0);
                accc[rf][cf] = __builtin_amdgcn_mfma_f32_16x16x32_f16(Al[rf], BhC[cf], accc[rf][cf], 0, 0, 0);
                accc[rf][cf] = __builtin_amdgcn_mfma_f32_16x16x32_f16(Ah[rf], BlC[cf], accc[rf][cf], 0, 0, 0);
            }

        if (!last) {
            union { _Float16 h[4]; uint2 u; } ph, pl;
            ph.h[0] = (_Float16)xn.x; pl.h[0] = (_Float16)((xn.x - (float)ph.h[0]) * 2048.0f);
            ph.h[1] = (_Float16)xn.y; pl.h[1] = (_Float16)((xn.y - (float)ph.h[1]) * 2048.0f);
            ph.h[2] = (_Float16)xn.z; pl.h[2] = (_Float16)((xn.z - (float)ph.h[2]) * 2048.0f);
            ph.h[3] = (_Float16)xn.w; pl.h[3] = (_Float16)((xn.w - (float)ph.h[3]) * 2048.0f);
            const int wb = base ^ 4096;
            *reinterpret_cast<uint2*>(&smem[wb + wr_off])        = ph.u;
            *reinterpret_cast<uint2*>(&smem[wb + 2048 + wr_off]) = pl.u;
            #pragma unroll
            for (int cf = 0; cf < 2; ++cf) { BhC[cf] = BhN[cf]; BlC[cf] = BlN[cf]; }
        }
        __syncthreads();
    }

    // ---- epilogue: logits -> LDS [32][128] f32 ----
    float* L = reinterpret_cast<float*>(smem);
    #pragma unroll
    for (int rf = 0; rf < 2; ++rf)
        #pragma unroll
        for (int cf = 0; cf < 2; ++cf) {
            const int col = colbase + cf * 16 + idx;
            #pragma unroll
            for (int q = 0; q < 4; ++q) {
                const int lrow = rf * 16 + g * 4 + q;
                L[lrow * ECOL + col] = accm[rf][cf][q] + accc[rf][cf][q] * 4.8828125e-4f;
            }
        }
    __syncthreads();

    // ---- fused softplus/noise/top-2/softmax: 8 threads per row ----
    {
        const int row = tid >> 3;          // 0..31
        const int j   = tid & 7;
        const int e0  = j * 8;
        const int grow = row_base + row;

        const float4 c0 = *reinterpret_cast<const float4*>(&L[row * ECOL + e0]);
        const float4 c1 = *reinterpret_cast<const float4*>(&L[row * ECOL + e0 + 4]);
        const float4 s0 = *reinterpret_cast<const float4*>(&L[row * ECOL + 64 + e0]);
        const float4 s1 = *reinterpret_cast<const float4*>(&L[row * ECOL + 64 + e0 + 4]);
        // clean logits out
        *reinterpret_cast<float4*>(&out[CLEAN_OFF + (size_t)grow * EDIM + e0])     = c0;
        *reinterpret_cast<float4*>(&out[CLEAN_OFF + (size_t)grow * EDIM + e0 + 4]) = c1;

        const float4 z0 = *reinterpret_cast<const float4*>(&noise[(size_t)grow * EDIM + e0]);
        const float4 z1 = *reinterpret_cast<const float4*>(&noise[(size_t)grow * EDIM + e0 + 4]);

        float nv[8];
        nv[0] = fmaf(softplus_f(s0.x), z0.x, c0.x);
        nv[1] = fmaf(softplus_f(s0.y), z0.y, c0.y);
        nv[2] = fmaf(softplus_f(s0.z), z0.z, c0.z);
        nv[3] = fmaf(softplus_f(s0.w), z0.w, c0.w);
        nv[4] = fmaf(softplus_f(s1.x), z1.x, c1.x);
        nv[5] = fmaf(softplus_f(s1.y), z1.y, c1.y);
        nv[6] = fmaf(softplus_f(s1.z), z1.z, c1.z);
        nv[7] = fmaf(softplus_f(s1.w), z1.w, c1.w);

        float v0 = nv[0], v1 = -INFINITY;
        int   i0 = e0,    i1 = -1;
        #pragma unroll
        for (int m = 1; m < 8; ++m) {
            const float v = nv[m]; const int e = e0 + m;
            if (v > v0)      { v1 = v0; i1 = i0; v0 = v; i0 = e; }
            else if (v > v1) { v1 = v;  i1 = e; }
        }
        #pragma unroll
        for (int d = 1; d < 8; d <<= 1) {
            const float ov0 = __shfl_xor(v0, d); const int oi0 = __shfl_xor(i0, d);
            const float ov1 = __shfl_xor(v1, d); const int oi1 = __shfl_xor(i1, d);
            const bool aFirst = (v0 > ov0) || (v0 == ov0 && i0 < oi0);
            float n0, n1; int ni0, ni1;
            if (aFirst) {
                n0 = v0; ni0 = i0;
                const bool s = (v1 > ov0) || (v1 == ov0 && i1 < oi0);
                n1 = s ? v1 : ov0; ni1 = s ? i1 : oi0;
            } else {
                n0 = ov0; ni0 = oi0;
                const bool s = (ov1 > v0) || (ov1 == v0 && oi1 < i0);
                n1 = s ? ov1 : v0; ni1 = s ? oi1 : i0;
            }
            v0 = n0; i0 = ni0; v1 = n1; i1 = ni1;
        }
        if (j == 0) {
            const float ex = expf(v1 - v0);          // <= 1
            const float w0 = 1.0f / (1.0f + ex);
            const float w1 = 1.0f - w0;
            out[(size_t)grow * 2 + 0] = w0;
            out[(size_t)grow * 2 + 1] = w1;
            out[IDX_OFF + (size_t)grow * 2 + 0] = (float)i0;
            out[IDX_OFF + (size_t)grow * 2 + 1] = (float)i1;
        }
    }
}

extern "C" void kernel_launch(void* const* d_in, const int* in_sizes, int n_in,
                              void* d_out, int out_size, void* d_ws, size_t ws_size,
                              hipStream_t stream) {
    const float* x     = (const float*)d_in[0];
    const float* Wg    = (const float*)d_in[1];
    const float* Wn    = (const float*)d_in[2];
    const float* noise = (const float*)d_in[3];
    float* out = (float*)d_out;

    _Float16* wh = (_Float16*)d_ws;
    _Float16* wl = wh + (size_t)ECOL * DDIM;     // +512KB

    split_w_kernel<<<dim3(256), dim3(256), 0, stream>>>(Wg, Wn, wh, wl);
    gating_mfma_kernel<<<dim3(NROWS / BM), dim3(256), 0, stream>>>(x, noise, wh, wl, out);
}